// Round 17
// baseline (141.697 us; speedup 1.0000x reference)
//
#include <hip/hip_runtime.h>
#include <hip/hip_bf16.h>

#define N_NODES 100000
#define N_EDGES 3200000
#define DIM 128
#define HID 32

#define BSH 6                                   // bucket = dst >> 6
#define BNODES (1 << BSH)                       // 64 nodes per bucket
#define NBUK ((N_NODES + BNODES - 1) >> BSH)    // 1563
#define NBP 2048                                // padded (pow2) bucket count
#define FCHUNK 8192                             // edges per partition block (391 blocks)
#define NFILL ((N_EDGES + FCHUNK - 1) / FCHUNK) // 391
#define CAP 3072                                // fixed slab per bucket (mean 2048, +22 sigma)

typedef short v8s __attribute__((ext_vector_type(8)));
typedef float v4f __attribute__((ext_vector_type(4)));

__device__ __forceinline__ float bf_lo(unsigned int u) { return __uint_as_float(u << 16); }
// maskless hi: low 16 garbage bits sit below the bf16 mantissa (<=2^-7 rel noise)
__device__ __forceinline__ float bf_hn(unsigned int u) { return __uint_as_float(u); }
__device__ __forceinline__ float bf_hi(unsigned int u) { return __uint_as_float(u & 0xFFFF0000u); }
__device__ __forceinline__ unsigned int pk2(float a, float b) {
    __hip_bfloat162 p = __float22bfloat162_rn(make_float2(a, b));
    union { __hip_bfloat162 h; unsigned int u; } cv; cv.h = p; return cv.u;
}

// Workspace: bcnt[NBP] y2[N] (both memset-0) ebuf[NBUK*CAP] rowbeg[N] rowend[N] dinv[N]
//            y1a[N*8] y1b[N*8]

// Partition edges into per-bucket slabs (ebuf[b*CAP ...]). SINGLE-PASS: edges held in
// registers, rank from the returning LDS atomicAdd; global base = b*CAP + bcnt bump.
// packed edge = (dst & 63) << 20 | src   (src < 2^17)
__launch_bounds__(512)
__global__ void k_bfill(const int* __restrict__ src, const int* __restrict__ dst,
                        int* __restrict__ bcnt, unsigned int* __restrict__ ebuf) {
    __shared__ int cntA[NBP];               // chunk-local counts
    __shared__ int offA[NBP];               // exclusive offsets within chunk
    __shared__ int diff[NBP];               // slabBase - offA  (single LDS read in flush)
    __shared__ int ssum[512];
    __shared__ unsigned int stage[FCHUNK];  // 32 KB
    __shared__ unsigned short sbuk[FCHUNK]; // 16 KB: bucket id per stage slot
    int t = threadIdx.x;
    int e0 = blockIdx.x * FCHUNK;
    int eN = min(e0 + FCHUNK, N_EDGES) - e0;       // multiple of 4
    int n4 = eN >> 2;
    const int4* d4 = (const int4*)(dst + e0);
    const int4* s4 = (const int4*)(src + e0);
    int4 dd[4], ss[4];
    #pragma unroll
    for (int k = 0; k < 4; ++k) {
        int i = t + k * 512;
        if (i < n4) { dd[k] = d4[i]; ss[k] = s4[i]; }   // issued up-front, independent
    }
    for (int i = t; i < NBP; i += 512) cntA[i] = 0;
    __syncthreads();
    // count + rank in one round (returning atomics)
    unsigned short rk[16];
    #pragma unroll
    for (int k = 0; k < 4; ++k) {
        int i = t + k * 512;
        if (i < n4) {
            rk[4 * k + 0] = (unsigned short)atomicAdd(&cntA[dd[k].x >> BSH], 1);
            rk[4 * k + 1] = (unsigned short)atomicAdd(&cntA[dd[k].y >> BSH], 1);
            rk[4 * k + 2] = (unsigned short)atomicAdd(&cntA[dd[k].z >> BSH], 1);
            rk[4 * k + 3] = (unsigned short)atomicAdd(&cntA[dd[k].w >> BSH], 1);
        }
    }
    __syncthreads();
    // LDS exclusive scan cntA -> offA (4 elems/thread)
    {
        int c[4]; int sum = 0;
        #pragma unroll
        for (int k = 0; k < 4; ++k) { c[k] = cntA[t * 4 + k]; sum += c[k]; }
        ssum[t] = sum; __syncthreads();
        for (int d = 1; d < 512; d <<= 1) {
            int add = (t >= d) ? ssum[t - d] : 0;
            __syncthreads();
            ssum[t] += add;
            __syncthreads();
        }
        int excl = ssum[t] - sum;
        #pragma unroll
        for (int k = 0; k < 4; ++k) { offA[t * 4 + k] = excl; excl += c[k]; }
    }
    __syncthreads();
    // reserve global slab space per bucket; store base - offA
    for (int b = t; b < NBP; b += 512)
        if (cntA[b] > 0) diff[b] = b * CAP + atomicAdd(&bcnt[b], cntA[b]) - offA[b];
    // place packed edges into LDS stage from registers
    #pragma unroll
    for (int k = 0; k < 4; ++k) {
        int i = t + k * 512;
        if (i < n4) {
            int b0 = dd[k].x >> BSH, b1 = dd[k].y >> BSH;
            int b2 = dd[k].z >> BSH, b3 = dd[k].w >> BSH;
            int p0 = offA[b0] + rk[4 * k + 0];
            int p1 = offA[b1] + rk[4 * k + 1];
            int p2 = offA[b2] + rk[4 * k + 2];
            int p3 = offA[b3] + rk[4 * k + 3];
            stage[p0] = ((unsigned int)(dd[k].x & (BNODES - 1)) << 20) | (unsigned int)ss[k].x;
            stage[p1] = ((unsigned int)(dd[k].y & (BNODES - 1)) << 20) | (unsigned int)ss[k].y;
            stage[p2] = ((unsigned int)(dd[k].z & (BNODES - 1)) << 20) | (unsigned int)ss[k].z;
            stage[p3] = ((unsigned int)(dd[k].w & (BNODES - 1)) << 20) | (unsigned int)ss[k].w;
            sbuk[p0] = (unsigned short)b0;
            sbuk[p1] = (unsigned short)b1;
            sbuk[p2] = (unsigned short)b2;
            sbuk[p3] = (unsigned short)b3;
        }
    }
    __syncthreads();
    // coalesced flush: consecutive i within a bucket run -> consecutive ebuf addrs
    for (int i = t; i < eN; i += 512)
        ebuf[diff[sbuk[i]] + i] = stage[i];
}

// Per-bucket LDS counting sort by dlocal -> slab dst-sorted (CSR runs).
// 4-way sub-bucketed histogram/cursors (sub = t&3) cut LDS-atomic contention 32->8 way.
__launch_bounds__(256)
__global__ void k_sort(unsigned int* __restrict__ ebuf, const int* __restrict__ bcnt,
                       int* __restrict__ rowbeg, int* __restrict__ rowend,
                       float* __restrict__ dinv) {
    __shared__ unsigned int slab[CAP];     // 12 KB
    __shared__ unsigned int slab2[CAP];    // 12 KB
    __shared__ int hist4[BNODES * 4];
    __shared__ int scanx[BNODES];
    __shared__ int cur4[BNODES * 4];
    int t = threadIdx.x;
    int b = blockIdx.x;
    int s0 = b * CAP;
    int n = min(bcnt[b], CAP);
    if (t < BNODES * 4) hist4[t] = 0;
    __syncthreads();
    int sub = t & 3;
    for (int i = t; i < n; i += 256) {
        unsigned int w = ebuf[s0 + i];
        slab[i] = w;
        atomicAdd(&hist4[((w >> 20) << 2) + sub], 1);
    }
    __syncthreads();
    if (t == 0) {
        int r = 0;
        for (int l = 0; l < BNODES; ++l) {
            scanx[l] = r;
            r += hist4[l * 4] + hist4[l * 4 + 1] + hist4[l * 4 + 2] + hist4[l * 4 + 3];
        }
    }
    __syncthreads();
    if (t < BNODES) {
        int h0 = hist4[t * 4], h1 = hist4[t * 4 + 1];
        int h2 = hist4[t * 4 + 2], h3 = hist4[t * 4 + 3];
        int base = scanx[t];
        cur4[t * 4 + 0] = base;
        cur4[t * 4 + 1] = base + h0;
        cur4[t * 4 + 2] = base + h0 + h1;
        cur4[t * 4 + 3] = base + h0 + h1 + h2;
        int deg = h0 + h1 + h2 + h3;
        int v = b * BNODES + t;
        if (v < N_NODES) {
            rowbeg[v] = s0 + base;
            rowend[v] = s0 + base + deg;
            dinv[v] = rsqrtf((float)(deg + 1));
        }
    }
    __syncthreads();
    for (int i = t; i < n; i += 256) {
        unsigned int w = slab[i];
        int pos = atomicAdd(&cur4[((w >> 20) << 2) + sub], 1);
        slab2[pos] = w;
    }
    __syncthreads();
    for (int i = t; i < n; i += 256) ebuf[s0 + i] = slab2[i];
}

// y1 = bf16-packed rows of dinv[v] * (x @ W1), via MFMA 16x16x32 bf16.
// Column-split output: y1a = cols 0..15 (32B rows), y1b = cols 16..31.
__launch_bounds__(256)
__global__ void k_gemm1(const float* __restrict__ x, const float* __restrict__ W1,
                        const float* __restrict__ dinv, unsigned int* __restrict__ y1a,
                        unsigned int* __restrict__ y1b) {
    int wv = (blockIdx.x * 256 + threadIdx.x) >> 6;
    int nwaves = (gridDim.x * 256) >> 6;
    int lane = threadIdx.x & 63;
    int m = lane & 15;
    int kb = lane >> 4;                   // 0..3
    v8s Bf[2][4];                         // B fragments: [ntile][kstep]
    #pragma unroll
    for (int tt = 0; tt < 2; ++tt)
        #pragma unroll
        for (int s = 0; s < 4; ++s) {
            union { unsigned int u[4]; v8s v; } ub;
            #pragma unroll
            for (int jj = 0; jj < 4; ++jj) {
                int k = s * 32 + kb * 8 + jj * 2;
                ub.u[jj] = pk2(W1[k * HID + tt * 16 + m], W1[(k + 1) * HID + tt * 16 + m]);
            }
            Bf[tt][s] = ub.v;
        }
    for (int tile = wv; tile < N_NODES / 16; tile += nwaves) {   // 6250 exact, no tail
        int base = tile * 16;
        const float* xr = x + (size_t)(base + m) * DIM;
        v4f acc0 = {0.f, 0.f, 0.f, 0.f}, acc1 = {0.f, 0.f, 0.f, 0.f};
        #pragma unroll
        for (int s = 0; s < 4; ++s) {
            float4 xa = *(const float4*)(xr + s * 32 + kb * 8);
            float4 xb = *(const float4*)(xr + s * 32 + kb * 8 + 4);
            union { unsigned int u[4]; v8s v; } ua;
            ua.u[0] = pk2(xa.x, xa.y); ua.u[1] = pk2(xa.z, xa.w);
            ua.u[2] = pk2(xb.x, xb.y); ua.u[3] = pk2(xb.z, xb.w);
            acc0 = __builtin_amdgcn_mfma_f32_16x16x32_bf16(ua.v, Bf[0][s], acc0, 0, 0, 0);
            acc1 = __builtin_amdgcn_mfma_f32_16x16x32_bf16(ua.v, Bf[1][s], acc1, 0, 0, 0);
        }
        float4 dv = *(const float4*)(dinv + base + kb * 4);     // rows kb*4..kb*4+3
        float d[4] = {dv.x, dv.y, dv.z, dv.w};
        #pragma unroll
        for (int r = 0; r < 4; ++r) {
            float v0 = acc0[r] * d[r];
            float v1 = acc1[r] * d[r];
            float p0 = __shfl_xor(v0, 1, 64);                   // partner col
            float p1 = __shfl_xor(v1, 1, 64);
            if ((m & 1) == 0) {
                int node = base + kb * 4 + r;
                y1a[node * 8 + (m >> 1)] = pk2(v0, p0);         // cols m, m+1
                y1b[node * 8 + (m >> 1)] = pk2(v1, p1);         // cols 16+m, 17+m
            }
        }
    }
}

// FUSED layer-1 gather, SHFL-FREE: half = blockIdx & 1 selects the L2-resident half-table.
// Lane = (edge-slot 0..7) x (uint2-col 0..3): each 4-lane group reads the SAME ebuf word
// directly (8 distinct words per 32-lane group = one merged 32B read, L1-broadcast) —
// the ds_bpermute hop and its latency are gone. 4 unrolled slots keep 4 ebuf + 4 row
// loads in flight. Hi-col unpack is maskless (noise below bf16 mantissa).
__launch_bounds__(256)
__global__ void k_gather1f(const int* __restrict__ rowbeg, const int* __restrict__ rowend,
                           const unsigned int* __restrict__ ebuf,
                           const unsigned int* __restrict__ y1a,
                           const unsigned int* __restrict__ y1b,
                           const float* __restrict__ dinv,
                           const float* __restrict__ b1, const float* __restrict__ W2,
                           float* __restrict__ out_h, float* __restrict__ y2acc) {
    int bid = blockIdx.x;
    int half = bid & 1;
    int t = threadIdx.x;
    int node = (bid >> 1) * 8 + (t >> 5);
    if (node >= N_NODES) return;
    const unsigned int* yh = half ? y1b : y1a;
    int lane = t & 31;
    int eslot = lane >> 2;                // edge slot 0..7 within a batch of 8
    int c2 = lane & 3;                    // uint2 index in 32B row (cols 4c2..4c2+3)
    int start = rowbeg[node], end = rowend[node];
    float a0[4] = {0.f, 0.f, 0.f, 0.f};
    float a1[4] = {0.f, 0.f, 0.f, 0.f};
    float a2[4] = {0.f, 0.f, 0.f, 0.f};
    float a3[4] = {0.f, 0.f, 0.f, 0.f};
    const uint2* y2b = (const uint2*)yh;
    int j = start;
    for (; j + 32 <= end; j += 32) {
        unsigned int w0 = ebuf[j + 0  + eslot];      // 4 direct reads, no shfl:
        unsigned int w1 = ebuf[j + 8  + eslot];      // each serves 4 lanes (merged)
        unsigned int w2 = ebuf[j + 16 + eslot];
        unsigned int w3 = ebuf[j + 24 + eslot];
        uint2 v0 = y2b[(size_t)(w0 & 0xFFFFF) * 4 + c2];   // 4 independent row loads
        uint2 v1 = y2b[(size_t)(w1 & 0xFFFFF) * 4 + c2];
        uint2 v2 = y2b[(size_t)(w2 & 0xFFFFF) * 4 + c2];
        uint2 v3 = y2b[(size_t)(w3 & 0xFFFFF) * 4 + c2];
        a0[0] += bf_lo(v0.x); a0[1] += bf_hn(v0.x); a0[2] += bf_lo(v0.y); a0[3] += bf_hn(v0.y);
        a1[0] += bf_lo(v1.x); a1[1] += bf_hn(v1.x); a1[2] += bf_lo(v1.y); a1[3] += bf_hn(v1.y);
        a2[0] += bf_lo(v2.x); a2[1] += bf_hn(v2.x); a2[2] += bf_lo(v2.y); a2[3] += bf_hn(v2.y);
        a3[0] += bf_lo(v3.x); a3[1] += bf_hn(v3.x); a3[2] += bf_lo(v3.y); a3[3] += bf_hn(v3.y);
    }
    int navail = end - j;                 // 0..31 tail edges
    if (navail > 0) {
        #pragma unroll
        for (int k = 0; k < 4; ++k) {
            int idx = k * 8 + eslot;
            unsigned int w = ebuf[min(j + idx, end - 1)];
            if (idx < navail) {
                uint2 v = y2b[(size_t)(w & 0xFFFFF) * 4 + c2];
                a0[0] += bf_lo(v.x); a0[1] += bf_hn(v.x);
                a0[2] += bf_lo(v.y); a0[3] += bf_hn(v.y);
            }
        }
    }
    float q[4];
    #pragma unroll
    for (int i = 0; i < 4; ++i) q[i] = (a0[i] + a1[i]) + (a2[i] + a3[i]);
    #pragma unroll
    for (int i = 0; i < 4; ++i) {
        q[i] += __shfl_xor(q[i], 4, 32);  // combine 8 edge slots
        q[i] += __shfl_xor(q[i], 8, 32);
        q[i] += __shfl_xor(q[i], 16, 32);
    }
    uint2 sv = y2b[(unsigned int)node * 4 + c2];     // self loop (exact unpack)
    q[0] += bf_lo(sv.x); q[1] += bf_hi(sv.x); q[2] += bf_lo(sv.y); q[3] += bf_hi(sv.y);
    float di = dinv[node];
    int col = half * 16 + 4 * c2;
    float h[4], p = 0.f;
    #pragma unroll
    for (int i = 0; i < 4; ++i) {
        h[i] = fmaxf(fmaf(di, q[i], b1[col + i]), 0.f);
        p = fmaf(h[i], W2[col + i], p);
    }
    p += __shfl_xor(p, 1, 32);            // reduce over the 4 c2 lanes
    p += __shfl_xor(p, 2, 32);
    if (eslot == 0) {
        *(float4*)&out_h[(size_t)node * HID + col] = make_float4(h[0], h[1], h[2], h[3]);
        if (c2 == 0) atomicAdd(&y2acc[node], di * p);
    }
}

// Layer-2 gather: 32 lanes stride the node's slab run (coalesced ebuf reads).
__launch_bounds__(256)
__global__ void k_gather2(const int* __restrict__ rowbeg, const int* __restrict__ rowend,
                          const unsigned int* __restrict__ ebuf, const float* __restrict__ y2,
                          const float* __restrict__ dinv, const float* __restrict__ b2,
                          float* __restrict__ scores) {
    int t = threadIdx.x;
    int node = blockIdx.x * 8 + (t >> 5);
    int lane = t & 31;
    if (node >= N_NODES) return;
    int start = rowbeg[node], end = rowend[node];
    float acc = 0.f;
    for (int j = start + lane; j < end; j += 32)
        acc += y2[ebuf[j] & 0xFFFFF];
    #pragma unroll
    for (int off = 16; off > 0; off >>= 1) acc += __shfl_xor(acc, off);
    if (lane == 0) scores[node] = dinv[node] * (acc + y2[node]) + b2[0];
}

extern "C" void kernel_launch(void* const* d_in, const int* in_sizes, int n_in,
                              void* d_out, int out_size, void* d_ws, size_t ws_size,
                              hipStream_t stream) {
    const float* x  = (const float*)d_in[0];
    const int* ei   = (const int*)d_in[1];
    const float* W1 = (const float*)d_in[2];
    const float* b1 = (const float*)d_in[3];
    const float* W2 = (const float*)d_in[4];
    const float* b2 = (const float*)d_in[5];

    const int* src = ei;             // edge_index[0]
    const int* dst = ei + N_EDGES;   // edge_index[1]

    int* bcnt = (int*)d_ws;                              // NBP       (memset 0)
    float* y2  = (float*)(bcnt + NBP);                   // N         (memset 0)
    unsigned int* ebuf = (unsigned int*)(y2 + N_NODES);  // NBUK*CAP (slabbed)
    int* rowbeg = (int*)(ebuf + (size_t)NBUK * CAP);     // N
    int* rowend = rowbeg + N_NODES;                      // N
    float* dinv = (float*)(rowend + N_NODES);            // N
    unsigned int* y1a = (unsigned int*)(dinv + N_NODES); // N*8 (bf16 cols 0..15)
    unsigned int* y1b = y1a + (size_t)N_NODES * 8;       // N*8 (bf16 cols 16..31)

    float* out_h = (float*)d_out;                        // N*HID
    float* out_s = out_h + (size_t)N_NODES * HID;        // N

    hipMemsetAsync(d_ws, 0, (NBP + N_NODES) * sizeof(int), stream);  // bcnt + y2
    k_bfill <<<NFILL, 512, 0, stream>>>(src, dst, bcnt, ebuf);
    k_sort  <<<NBUK, 256, 0, stream>>>(ebuf, bcnt, rowbeg, rowend, dinv);
    k_gemm1 <<<512, 256, 0, stream>>>(x, W1, dinv, y1a, y1b);
    k_gather1f<<<((N_NODES + 7) / 8) * 2, 256, 0, stream>>>(rowbeg, rowend, ebuf, y1a, y1b,
                                                            dinv, b1, W2, out_h, y2);
    k_gather2<<<(N_NODES + 7) / 8, 256, 0, stream>>>(rowbeg, rowend, ebuf, y2, dinv, b2, out_s);
}

// Round 18
// 134.659 us; speedup vs baseline: 1.0523x; 1.0523x over previous
//
#include <hip/hip_runtime.h>
#include <hip/hip_bf16.h>

#define N_NODES 100000
#define N_EDGES 3200000
#define DIM 128
#define HID 32

#define BSH 6                                   // bucket = dst >> 6
#define BNODES (1 << BSH)                       // 64 nodes per bucket
#define NBUK ((N_NODES + BNODES - 1) >> BSH)    // 1563
#define NBP 2048                                // padded (pow2) bucket count
#define FCHUNK 8192                             // edges per partition block (391 blocks)
#define NFILL ((N_EDGES + FCHUNK - 1) / FCHUNK) // 391
#define CAP 3072                                // fixed slab per bucket (mean 2048, +22 sigma)

typedef short v8s __attribute__((ext_vector_type(8)));
typedef float v4f __attribute__((ext_vector_type(4)));

__device__ __forceinline__ float bf_lo(unsigned int u) { return __uint_as_float(u << 16); }
__device__ __forceinline__ float bf_hi(unsigned int u) { return __uint_as_float(u & 0xFFFF0000u); }
__device__ __forceinline__ unsigned int pk2(float a, float b) {
    __hip_bfloat162 p = __float22bfloat162_rn(make_float2(a, b));
    union { __hip_bfloat162 h; unsigned int u; } cv; cv.h = p; return cv.u;
}

// Workspace: bcnt[NBP] y2[N] (both memset-0) ebuf[NBUK*CAP] rowbeg[N] rowend[N] dinv[N]
//            y1a[N*8] y1b[N*8]

// Partition edges into per-bucket slabs (ebuf[b*CAP ...]). SINGLE-PASS: edges held in
// registers, rank from the returning LDS atomicAdd; global base = b*CAP + bcnt bump.
// packed edge = (dst & 63) << 20 | src   (src < 2^17)
__launch_bounds__(512)
__global__ void k_bfill(const int* __restrict__ src, const int* __restrict__ dst,
                        int* __restrict__ bcnt, unsigned int* __restrict__ ebuf) {
    __shared__ int cntA[NBP];               // chunk-local counts
    __shared__ int offA[NBP];               // exclusive offsets within chunk
    __shared__ int diff[NBP];               // slabBase - offA  (single LDS read in flush)
    __shared__ int ssum[512];
    __shared__ unsigned int stage[FCHUNK];  // 32 KB
    __shared__ unsigned short sbuk[FCHUNK]; // 16 KB: bucket id per stage slot
    int t = threadIdx.x;
    int e0 = blockIdx.x * FCHUNK;
    int eN = min(e0 + FCHUNK, N_EDGES) - e0;       // multiple of 4
    int n4 = eN >> 2;
    const int4* d4 = (const int4*)(dst + e0);
    const int4* s4 = (const int4*)(src + e0);
    int4 dd[4], ss[4];
    #pragma unroll
    for (int k = 0; k < 4; ++k) {
        int i = t + k * 512;
        if (i < n4) { dd[k] = d4[i]; ss[k] = s4[i]; }   // issued up-front, independent
    }
    for (int i = t; i < NBP; i += 512) cntA[i] = 0;
    __syncthreads();
    // count + rank in one round (returning atomics)
    unsigned short rk[16];
    #pragma unroll
    for (int k = 0; k < 4; ++k) {
        int i = t + k * 512;
        if (i < n4) {
            rk[4 * k + 0] = (unsigned short)atomicAdd(&cntA[dd[k].x >> BSH], 1);
            rk[4 * k + 1] = (unsigned short)atomicAdd(&cntA[dd[k].y >> BSH], 1);
            rk[4 * k + 2] = (unsigned short)atomicAdd(&cntA[dd[k].z >> BSH], 1);
            rk[4 * k + 3] = (unsigned short)atomicAdd(&cntA[dd[k].w >> BSH], 1);
        }
    }
    __syncthreads();
    // LDS exclusive scan cntA -> offA (4 elems/thread)
    {
        int c[4]; int sum = 0;
        #pragma unroll
        for (int k = 0; k < 4; ++k) { c[k] = cntA[t * 4 + k]; sum += c[k]; }
        ssum[t] = sum; __syncthreads();
        for (int d = 1; d < 512; d <<= 1) {
            int add = (t >= d) ? ssum[t - d] : 0;
            __syncthreads();
            ssum[t] += add;
            __syncthreads();
        }
        int excl = ssum[t] - sum;
        #pragma unroll
        for (int k = 0; k < 4; ++k) { offA[t * 4 + k] = excl; excl += c[k]; }
    }
    __syncthreads();
    // reserve global slab space per bucket; store base - offA
    for (int b = t; b < NBP; b += 512)
        if (cntA[b] > 0) diff[b] = b * CAP + atomicAdd(&bcnt[b], cntA[b]) - offA[b];
    // place packed edges into LDS stage from registers
    #pragma unroll
    for (int k = 0; k < 4; ++k) {
        int i = t + k * 512;
        if (i < n4) {
            int b0 = dd[k].x >> BSH, b1 = dd[k].y >> BSH;
            int b2 = dd[k].z >> BSH, b3 = dd[k].w >> BSH;
            int p0 = offA[b0] + rk[4 * k + 0];
            int p1 = offA[b1] + rk[4 * k + 1];
            int p2 = offA[b2] + rk[4 * k + 2];
            int p3 = offA[b3] + rk[4 * k + 3];
            stage[p0] = ((unsigned int)(dd[k].x & (BNODES - 1)) << 20) | (unsigned int)ss[k].x;
            stage[p1] = ((unsigned int)(dd[k].y & (BNODES - 1)) << 20) | (unsigned int)ss[k].y;
            stage[p2] = ((unsigned int)(dd[k].z & (BNODES - 1)) << 20) | (unsigned int)ss[k].z;
            stage[p3] = ((unsigned int)(dd[k].w & (BNODES - 1)) << 20) | (unsigned int)ss[k].w;
            sbuk[p0] = (unsigned short)b0;
            sbuk[p1] = (unsigned short)b1;
            sbuk[p2] = (unsigned short)b2;
            sbuk[p3] = (unsigned short)b3;
        }
    }
    __syncthreads();
    // coalesced flush: consecutive i within a bucket run -> consecutive ebuf addrs
    for (int i = t; i < eN; i += 512)
        ebuf[diff[sbuk[i]] + i] = stage[i];
}

// Per-bucket LDS counting sort by dlocal -> slab dst-sorted (CSR runs).
// 4-way sub-bucketed histogram/cursors (sub = t&3) cut LDS-atomic contention 32->8 way.
__launch_bounds__(256)
__global__ void k_sort(unsigned int* __restrict__ ebuf, const int* __restrict__ bcnt,
                       int* __restrict__ rowbeg, int* __restrict__ rowend,
                       float* __restrict__ dinv) {
    __shared__ unsigned int slab[CAP];     // 12 KB
    __shared__ unsigned int slab2[CAP];    // 12 KB
    __shared__ int hist4[BNODES * 4];
    __shared__ int scanx[BNODES];
    __shared__ int cur4[BNODES * 4];
    int t = threadIdx.x;
    int b = blockIdx.x;
    int s0 = b * CAP;
    int n = min(bcnt[b], CAP);
    if (t < BNODES * 4) hist4[t] = 0;
    __syncthreads();
    int sub = t & 3;
    for (int i = t; i < n; i += 256) {
        unsigned int w = ebuf[s0 + i];
        slab[i] = w;
        atomicAdd(&hist4[((w >> 20) << 2) + sub], 1);
    }
    __syncthreads();
    if (t == 0) {
        int r = 0;
        for (int l = 0; l < BNODES; ++l) {
            scanx[l] = r;
            r += hist4[l * 4] + hist4[l * 4 + 1] + hist4[l * 4 + 2] + hist4[l * 4 + 3];
        }
    }
    __syncthreads();
    if (t < BNODES) {
        int h0 = hist4[t * 4], h1 = hist4[t * 4 + 1];
        int h2 = hist4[t * 4 + 2], h3 = hist4[t * 4 + 3];
        int base = scanx[t];
        cur4[t * 4 + 0] = base;
        cur4[t * 4 + 1] = base + h0;
        cur4[t * 4 + 2] = base + h0 + h1;
        cur4[t * 4 + 3] = base + h0 + h1 + h2;
        int deg = h0 + h1 + h2 + h3;
        int v = b * BNODES + t;
        if (v < N_NODES) {
            rowbeg[v] = s0 + base;
            rowend[v] = s0 + base + deg;
            dinv[v] = rsqrtf((float)(deg + 1));
        }
    }
    __syncthreads();
    for (int i = t; i < n; i += 256) {
        unsigned int w = slab[i];
        int pos = atomicAdd(&cur4[((w >> 20) << 2) + sub], 1);
        slab2[pos] = w;
    }
    __syncthreads();
    for (int i = t; i < n; i += 256) ebuf[s0 + i] = slab2[i];
}

// y1 = bf16-packed rows of dinv[v] * (x @ W1), via MFMA 16x16x32 bf16.
// Column-split output: y1a = cols 0..15 (32B rows), y1b = cols 16..31.
__launch_bounds__(256)
__global__ void k_gemm1(const float* __restrict__ x, const float* __restrict__ W1,
                        const float* __restrict__ dinv, unsigned int* __restrict__ y1a,
                        unsigned int* __restrict__ y1b) {
    int wv = (blockIdx.x * 256 + threadIdx.x) >> 6;
    int nwaves = (gridDim.x * 256) >> 6;
    int lane = threadIdx.x & 63;
    int m = lane & 15;
    int kb = lane >> 4;                   // 0..3
    v8s Bf[2][4];                         // B fragments: [ntile][kstep]
    #pragma unroll
    for (int tt = 0; tt < 2; ++tt)
        #pragma unroll
        for (int s = 0; s < 4; ++s) {
            union { unsigned int u[4]; v8s v; } ub;
            #pragma unroll
            for (int jj = 0; jj < 4; ++jj) {
                int k = s * 32 + kb * 8 + jj * 2;
                ub.u[jj] = pk2(W1[k * HID + tt * 16 + m], W1[(k + 1) * HID + tt * 16 + m]);
            }
            Bf[tt][s] = ub.v;
        }
    for (int tile = wv; tile < N_NODES / 16; tile += nwaves) {   // 6250 exact, no tail
        int base = tile * 16;
        const float* xr = x + (size_t)(base + m) * DIM;
        v4f acc0 = {0.f, 0.f, 0.f, 0.f}, acc1 = {0.f, 0.f, 0.f, 0.f};
        #pragma unroll
        for (int s = 0; s < 4; ++s) {
            float4 xa = *(const float4*)(xr + s * 32 + kb * 8);
            float4 xb = *(const float4*)(xr + s * 32 + kb * 8 + 4);
            union { unsigned int u[4]; v8s v; } ua;
            ua.u[0] = pk2(xa.x, xa.y); ua.u[1] = pk2(xa.z, xa.w);
            ua.u[2] = pk2(xb.x, xb.y); ua.u[3] = pk2(xb.z, xb.w);
            acc0 = __builtin_amdgcn_mfma_f32_16x16x32_bf16(ua.v, Bf[0][s], acc0, 0, 0, 0);
            acc1 = __builtin_amdgcn_mfma_f32_16x16x32_bf16(ua.v, Bf[1][s], acc1, 0, 0, 0);
        }
        float4 dv = *(const float4*)(dinv + base + kb * 4);     // rows kb*4..kb*4+3
        float d[4] = {dv.x, dv.y, dv.z, dv.w};
        #pragma unroll
        for (int r = 0; r < 4; ++r) {
            float v0 = acc0[r] * d[r];
            float v1 = acc1[r] * d[r];
            float p0 = __shfl_xor(v0, 1, 64);                   // partner col
            float p1 = __shfl_xor(v1, 1, 64);
            if ((m & 1) == 0) {
                int node = base + kb * 4 + r;
                y1a[node * 8 + (m >> 1)] = pk2(v0, p0);         // cols m, m+1
                y1b[node * 8 + (m >> 1)] = pk2(v1, p1);         // cols 16+m, 17+m
            }
        }
    }
}

// FUSED layer-1 gather: half = blockIdx & 1 selects the L2-resident half-table.
// With round-robin blockIdx->XCD mapping, even XCDs cache y1a, odd cache y1b —
// per-XCD working set stays 3.2MB (< 4MB L2). Correct under ANY mapping.
// 32 lanes per node = 8 edge-subsets x 4 uint2-lanes; 4 independent 8B loads per
// batch of 32 edges. y2 += dinv*(h.W2half) via atomicAdd (2 commutative adds).
__launch_bounds__(256)
__global__ void k_gather1f(const int* __restrict__ rowbeg, const int* __restrict__ rowend,
                           const unsigned int* __restrict__ ebuf,
                           const unsigned int* __restrict__ y1a,
                           const unsigned int* __restrict__ y1b,
                           const float* __restrict__ dinv,
                           const float* __restrict__ b1, const float* __restrict__ W2,
                           float* __restrict__ out_h, float* __restrict__ y2acc) {
    int bid = blockIdx.x;
    int half = bid & 1;
    int t = threadIdx.x;
    int node = (bid >> 1) * 8 + (t >> 5);
    if (node >= N_NODES) return;
    const unsigned int* yh = half ? y1b : y1a;
    int lane = t & 31;
    int sub = lane >> 2;                  // edge subset 0..7
    int c2 = lane & 3;                    // uint2 index in 32B row (cols 4c2..4c2+3)
    int start = rowbeg[node], end = rowend[node];
    float a0[4] = {0.f, 0.f, 0.f, 0.f};
    float a1[4] = {0.f, 0.f, 0.f, 0.f};
    float a2[4] = {0.f, 0.f, 0.f, 0.f};
    float a3[4] = {0.f, 0.f, 0.f, 0.f};
    const uint2* y2b = (const uint2*)yh;
    int j = start;
    for (; j + 32 <= end; j += 32) {
        unsigned int w = ebuf[j + lane];             // 32 consecutive words
        unsigned int e0 = (unsigned int)__shfl((int)w, 0  + sub, 32) & 0xFFFFF;
        unsigned int e1 = (unsigned int)__shfl((int)w, 8  + sub, 32) & 0xFFFFF;
        unsigned int e2 = (unsigned int)__shfl((int)w, 16 + sub, 32) & 0xFFFFF;
        unsigned int e3 = (unsigned int)__shfl((int)w, 24 + sub, 32) & 0xFFFFF;
        uint2 v0 = y2b[e0 * 4 + c2];                 // 4 independent 8B row loads
        uint2 v1 = y2b[e1 * 4 + c2];
        uint2 v2 = y2b[e2 * 4 + c2];
        uint2 v3 = y2b[e3 * 4 + c2];
        a0[0] += bf_lo(v0.x); a0[1] += bf_hi(v0.x); a0[2] += bf_lo(v0.y); a0[3] += bf_hi(v0.y);
        a1[0] += bf_lo(v1.x); a1[1] += bf_hi(v1.x); a1[2] += bf_lo(v1.y); a1[3] += bf_hi(v1.y);
        a2[0] += bf_lo(v2.x); a2[1] += bf_hi(v2.x); a2[2] += bf_lo(v2.y); a2[3] += bf_hi(v2.y);
        a3[0] += bf_lo(v3.x); a3[1] += bf_hi(v3.x); a3[2] += bf_lo(v3.y); a3[3] += bf_hi(v3.y);
    }
    int navail = end - j;                 // 0..31 tail edges
    if (navail > 0) {
        unsigned int w = ebuf[min(j + lane, end - 1)];
        #pragma unroll
        for (int k = 0; k < 4; ++k) {
            int idx = k * 8 + sub;
            unsigned int u = (unsigned int)__shfl((int)w, idx, 32) & 0xFFFFF;
            if (idx < navail) {
                uint2 v = y2b[u * 4 + c2];
                a0[0] += bf_lo(v.x); a0[1] += bf_hi(v.x);
                a0[2] += bf_lo(v.y); a0[3] += bf_hi(v.y);
            }
        }
    }
    float q[4];
    #pragma unroll
    for (int i = 0; i < 4; ++i) q[i] = (a0[i] + a1[i]) + (a2[i] + a3[i]);
    #pragma unroll
    for (int i = 0; i < 4; ++i) {
        q[i] += __shfl_xor(q[i], 4, 32);  // combine 8 edge subsets
        q[i] += __shfl_xor(q[i], 8, 32);
        q[i] += __shfl_xor(q[i], 16, 32);
    }
    uint2 sv = y2b[(unsigned int)node * 4 + c2];     // self loop
    q[0] += bf_lo(sv.x); q[1] += bf_hi(sv.x); q[2] += bf_lo(sv.y); q[3] += bf_hi(sv.y);
    float di = dinv[node];
    int col = half * 16 + 4 * c2;
    float h[4], p = 0.f;
    #pragma unroll
    for (int i = 0; i < 4; ++i) {
        h[i] = fmaxf(fmaf(di, q[i], b1[col + i]), 0.f);
        p = fmaf(h[i], W2[col + i], p);
    }
    p += __shfl_xor(p, 1, 32);            // reduce over the 4 c2 lanes
    p += __shfl_xor(p, 2, 32);
    if (sub == 0) {
        *(float4*)&out_h[(size_t)node * HID + col] = make_float4(h[0], h[1], h[2], h[3]);
        if (c2 == 0) atomicAdd(&y2acc[node], di * p);
    }
}

// Layer-2 gather: 32 lanes stride the node's slab run (coalesced ebuf reads).
__launch_bounds__(256)
__global__ void k_gather2(const int* __restrict__ rowbeg, const int* __restrict__ rowend,
                          const unsigned int* __restrict__ ebuf, const float* __restrict__ y2,
                          const float* __restrict__ dinv, const float* __restrict__ b2,
                          float* __restrict__ scores) {
    int t = threadIdx.x;
    int node = blockIdx.x * 8 + (t >> 5);
    int lane = t & 31;
    if (node >= N_NODES) return;
    int start = rowbeg[node], end = rowend[node];
    float acc = 0.f;
    for (int j = start + lane; j < end; j += 32)
        acc += y2[ebuf[j] & 0xFFFFF];
    #pragma unroll
    for (int off = 16; off > 0; off >>= 1) acc += __shfl_xor(acc, off);
    if (lane == 0) scores[node] = dinv[node] * (acc + y2[node]) + b2[0];
}

extern "C" void kernel_launch(void* const* d_in, const int* in_sizes, int n_in,
                              void* d_out, int out_size, void* d_ws, size_t ws_size,
                              hipStream_t stream) {
    const float* x  = (const float*)d_in[0];
    const int* ei   = (const int*)d_in[1];
    const float* W1 = (const float*)d_in[2];
    const float* b1 = (const float*)d_in[3];
    const float* W2 = (const float*)d_in[4];
    const float* b2 = (const float*)d_in[5];

    const int* src = ei;             // edge_index[0]
    const int* dst = ei + N_EDGES;   // edge_index[1]

    int* bcnt = (int*)d_ws;                              // NBP       (memset 0)
    float* y2  = (float*)(bcnt + NBP);                   // N         (memset 0)
    unsigned int* ebuf = (unsigned int*)(y2 + N_NODES);  // NBUK*CAP (slabbed)
    int* rowbeg = (int*)(ebuf + (size_t)NBUK * CAP);     // N
    int* rowend = rowbeg + N_NODES;                      // N
    float* dinv = (float*)(rowend + N_NODES);            // N
    unsigned int* y1a = (unsigned int*)(dinv + N_NODES); // N*8 (bf16 cols 0..15)
    unsigned int* y1b = y1a + (size_t)N_NODES * 8;       // N*8 (bf16 cols 16..31)

    float* out_h = (float*)d_out;                        // N*HID
    float* out_s = out_h + (size_t)N_NODES * HID;        // N

    hipMemsetAsync(d_ws, 0, (NBP + N_NODES) * sizeof(int), stream);  // bcnt + y2
    k_bfill <<<NFILL, 512, 0, stream>>>(src, dst, bcnt, ebuf);
    k_sort  <<<NBUK, 256, 0, stream>>>(ebuf, bcnt, rowbeg, rowend, dinv);
    k_gemm1 <<<512, 256, 0, stream>>>(x, W1, dinv, y1a, y1b);
    k_gather1f<<<((N_NODES + 7) / 8) * 2, 256, 0, stream>>>(rowbeg, rowend, ebuf, y1a, y1b,
                                                            dinv, b1, W2, out_h, y2);
    k_gather2<<<(N_NODES + 7) / 8, 256, 0, stream>>>(rowbeg, rowend, ebuf, y2, dinv, b2, out_s);
}